// Round 6
// baseline (326.187 us; speedup 1.0000x reference)
//
#include <hip/hip_runtime.h>
#include <hip/hip_bf16.h>

// QDense: out = s * (U X U^H)[:128,:128] / tr + (1-s) * diag(softmax(rand_w))
// B=512, D=256, O=128.
// Round-6: two barrier-free streaming kernels through a fragment-packed Y scratch.
//   K1 (1024 blocks = (b,kh), 512 thr): Y[:, kh*64..] = X * U_half^H.
//       U-half in swizzled LDS (one barrier), waves free-run 4 passes,
//       accumulator fragments stored RAW to global (8 B/lane, coalesced).
//   K2 (512 blocks = b, 512 thr): sub = U_sub * Y, trace from sub diagonal,
//       normalize/blend epilogue.  A = U rows (global), B = Y frags (global,
//       lane-permuted coalesced reads).  r2-K2 proven structure.
//
// Y fragment layout: frag(b, kg, jg) holds rows j = jg*16+(g4*4+r),
// cols k' = kg*16+c16; lane fl = g4*16+c16 stores 4 shorts (r=0..3) at
//   PK(b,kg,jg,fl) = (((b*8+kg)*16+jg)*64+fl)*4   [shorts]
// K2 B-frag for (kg, j-block ks*32): lane (c16,g4) needs j = ks*32+g4*8+e:
//   jg = ks*2+(g4>>1); e=0..3 from src lane (g4&1)*32+c16, e=4..7 from +16.
//   Both are 8 B reads, 32 lanes contiguous per jg -> coalesced.

typedef __attribute__((ext_vector_type(4))) float f32x4;
typedef __attribute__((ext_vector_type(8))) short bf16x8;

static __device__ __forceinline__ short f2bf(float f) {   // prep kernels only
    unsigned u = __float_as_uint(f);
    u += 0x7fffu + ((u >> 16) & 1u);
    return (short)(u >> 16);
}

static __device__ __forceinline__ unsigned cvtpk2(float lo, float hi) {
    union { __hip_bfloat162 h; unsigned u; } c;
    c.h = __float22bfloat162_rn(float2{lo, hi});
    return c.u;
}

static __device__ __forceinline__ bf16x8 pack8(f32x4 a, f32x4 b) {
    union { unsigned u[4]; bf16x8 v; } r;
    r.u[0] = cvtpk2(a[0], a[1]);
    r.u[1] = cvtpk2(a[2], a[3]);
    r.u[2] = cvtpk2(b[0], b[1]);
    r.u[3] = cvtpk2(b[2], b[3]);
    return r.v;
}

static __device__ __forceinline__ f32x4 mfma16(bf16x8 a, bf16x8 b, f32x4 c) {
    return __builtin_amdgcn_mfma_f32_16x16x32_bf16(a, b, c, 0, 0, 0);
}

// ---- prep: convert U rows [0,128) to bf16 (weight is (D,D,2) interleaved) ----
__global__ void qprep_u(const float* __restrict__ wt,
                        short* __restrict__ Ur, short* __restrict__ Ui) {
    int idx = blockIdx.x * 256 + threadIdx.x;         // j*256+k, j<128
    float2 v = ((const float2*)wt)[idx];
    Ur[idx] = f2bf(v.x);
    Ui[idx] = f2bf(v.y);
}

// ---- prep: p = softmax(rand_w), s = sigmoid(lam) ----
__global__ void qprep_ps(const float* __restrict__ rw, const float* __restrict__ lm,
                         float* __restrict__ pv, float* __restrict__ sv) {
    int t = threadIdx.x;                               // 64 threads
    float w0 = rw[t], w1 = rw[t + 64];
    float m = fmaxf(w0, w1);
    #pragma unroll
    for (int o = 32; o > 0; o >>= 1) m = fmaxf(m, __shfl_xor(m, o));
    float e0 = expf(w0 - m), e1 = expf(w1 - m);
    float ss = e0 + e1;
    #pragma unroll
    for (int o = 32; o > 0; o >>= 1) ss += __shfl_xor(ss, o);
    pv[t] = e0 / ss;
    pv[t + 64] = e1 / ss;
    if (t == 0) sv[0] = 1.f / (1.f + expf(-lm[0]));
}

// ---- K1: Y frags = X * U_half^H.  One barrier, then free-run. ----
__global__ __launch_bounds__(512, 4) void qk1(
    const float* __restrict__ xr, const float* __restrict__ xi,
    const short* __restrict__ Urg, const short* __restrict__ Uig,
    short* __restrict__ Ypr, short* __restrict__ Ypi)
{
    // LDS: U-half 64 rows (k') x 512 B, XOR-swizzled; R at 0, I at 32768.
    __shared__ __align__(16) char smem[65536];

    const int bx   = blockIdx.x;
    const int b    = bx >> 1;
    const int kh   = bx & 1;
    const int tid  = threadIdx.x;
    const int lane = tid & 63;
    const int w    = tid >> 6;           // 0..7
    const int c16  = lane & 15;
    const int g4   = lane >> 4;          // 0..3

    // stage U-half into swizzled LDS (source-slot permutation)  [r3-proven]
    #pragma unroll
    for (int q = 0; q < 4; ++q) {
        int c    = tid + q * 512;        // 2048 chunks of 16 B per plane
        int row  = c >> 5;               // 0..63
        int slot = c & 31;
        int ss   = slot ^ (row & 7);
        const short* sr = Urg + (size_t)(kh * 64 + row) * 256 + ss * 8;
        const short* si = Uig + (size_t)(kh * 64 + row) * 256 + ss * 8;
        *(bf16x8*)(smem + row * 512 + slot * 16)         = *(const bf16x8*)sr;
        *(bf16x8*)(smem + 32768 + row * 512 + slot * 16) = *(const bf16x8*)si;
    }
    __syncthreads();                      // the ONLY barrier

    const float* xrb = xr + ((size_t)b << 16);
    const float* xib = xi + ((size_t)b << 16);

    const int ja = (w & 3) * 16;          // j-group within pass
    const int kb = (w >> 2) * 32;         // k'-group (local to half)

    f32x4 zero = {0.f, 0.f, 0.f, 0.f};

    for (int jt = 0; jt < 256; jt += 64) {       // 4 independent passes
        f32x4 yR[2], yI[2];
        yR[0] = zero; yR[1] = zero; yI[0] = zero; yI[1] = zero;

        const int jrow = jt + ja + c16;
        const float* xr_row = xrb + (size_t)jrow * 256 + g4 * 8;
        const float* xi_row = xib + (size_t)jrow * 256 + g4 * 8;

        #pragma unroll
        for (int ks = 0; ks < 8; ++ks) {
            f32x4 a0 = *(const f32x4*)(xr_row + ks * 32);
            f32x4 a1 = *(const f32x4*)(xr_row + ks * 32 + 4);
            f32x4 b0 = *(const f32x4*)(xi_row + ks * 32);
            f32x4 b1 = *(const f32x4*)(xi_row + ks * 32 + 4);
            bf16x8 axr  = pack8(a0, a1);
            bf16x8 axi  = pack8(b0, b1);
            bf16x8 axrn = axr ^ (short)0x8000;

            #pragma unroll
            for (int nt = 0; nt < 2; ++nt) {
                int kloc = kb + nt * 16 + c16;
                int off  = kloc * 512 + ((ks * 64 + g4 * 16) ^ ((kloc & 7) << 4));
                bf16x8 bur = *(const bf16x8*)(smem + off);
                bf16x8 bui = *(const bf16x8*)(smem + 32768 + off);
                // Yr = Xr Ur^T + Xi Ui^T ; Yi = Xi Ur^T - Xr Ui^T
                yR[nt] = mfma16(axr,  bur, yR[nt]);
                yR[nt] = mfma16(axi,  bui, yR[nt]);
                yI[nt] = mfma16(axi,  bur, yI[nt]);
                yI[nt] = mfma16(axrn, bui, yI[nt]);
            }
        }

        // store raw fragments, coalesced 8 B/lane
        #pragma unroll
        for (int nt = 0; nt < 2; ++nt) {
            int kg = kh * 4 + (w >> 2) * 2 + nt;
            int jg = (jt >> 4) + (w & 3);
            size_t po = ((((size_t)b * 8 + kg) * 16 + jg) * 64 + lane) * 4;
            uint2 vr, vi;
            vr.x = cvtpk2(yR[nt][0], yR[nt][1]);
            vr.y = cvtpk2(yR[nt][2], yR[nt][3]);
            vi.x = cvtpk2(yI[nt][0], yI[nt][1]);
            vi.y = cvtpk2(yI[nt][2], yI[nt][3]);
            *(uint2*)(Ypr + po) = vr;
            *(uint2*)(Ypi + po) = vi;
        }
    }
}

// ---- K2: sub = U_sub * Y + trace/normalize/blend.  No staging. ----
__global__ __launch_bounds__(512, 2) void qk2(
    const short* __restrict__ Urg, const short* __restrict__ Uig,
    const short* __restrict__ Ypr, const short* __restrict__ Ypi,
    const float* __restrict__ pv, const float* __restrict__ sv,
    float* __restrict__ out)
{
    __shared__ float red[8];
    const int b    = blockIdx.x;
    const int tid  = threadIdx.x;
    const int lane = tid & 63;
    const int w    = tid >> 6;
    const int c16  = lane & 15;
    const int g4   = lane >> 4;
    const int wm   = w >> 2;             // i-half
    const int wn   = w & 3;              // k'-quarter

    f32x4 zero = {0.f, 0.f, 0.f, 0.f};
    f32x4 sR[4][2], sI[4][2];
    #pragma unroll
    for (int m = 0; m < 4; ++m)
        #pragma unroll
        for (int n = 0; n < 2; ++n) { sR[m][n] = zero; sI[m][n] = zero; }

    #pragma unroll 2
    for (int ks = 0; ks < 8; ++ks) {       // contraction over j, 32 per step
        bf16x8 aur[4], aui[4], auin[4];
        #pragma unroll
        for (int mt = 0; mt < 4; ++mt) {
            int i = wm * 64 + mt * 16 + c16;
            aur[mt]  = *(const bf16x8*)(Urg + (size_t)i * 256 + ks * 32 + g4 * 8);
            aui[mt]  = *(const bf16x8*)(Uig + (size_t)i * 256 + ks * 32 + g4 * 8);
            auin[mt] = aui[mt] ^ (short)0x8000;
        }
        #pragma unroll
        for (int nt = 0; nt < 2; ++nt) {
            int kg = wn * 2 + nt;
            int jg = ks * 2 + (g4 >> 1);
            size_t base = (((size_t)b * 8 + kg) * 16 + jg) * 64;
            int l0 = (g4 & 1) * 32 + c16;
            union { uint2 u2[2]; bf16x8 v; } br, bi;
            br.u2[0] = *(const uint2*)(Ypr + (base + l0) * 4);
            br.u2[1] = *(const uint2*)(Ypr + (base + l0 + 16) * 4);
            bi.u2[0] = *(const uint2*)(Ypi + (base + l0) * 4);
            bi.u2[1] = *(const uint2*)(Ypi + (base + l0 + 16) * 4);
            #pragma unroll
            for (int mt = 0; mt < 4; ++mt) {
                // sub_r = Ur Yr - Ui Yi ; sub_i = Ui Yr + Ur Yi
                sR[mt][nt] = mfma16(aur[mt],  br.v, sR[mt][nt]);
                sR[mt][nt] = mfma16(auin[mt], bi.v, sR[mt][nt]);
                sI[mt][nt] = mfma16(aui[mt],  br.v, sI[mt][nt]);
                sI[mt][nt] = mfma16(aur[mt],  bi.v, sI[mt][nt]);
            }
        }
    }

    // ---------- trace from sub diagonal ----------
    float loc = 0.f;
    #pragma unroll
    for (int mt = 0; mt < 4; ++mt)
        #pragma unroll
        for (int nt = 0; nt < 2; ++nt) {
            int colc = wn * 32 + nt * 16 + c16;
            #pragma unroll
            for (int r = 0; r < 4; ++r) {
                int row = wm * 64 + mt * 16 + g4 * 4 + r;
                if (row == colc) loc += sR[mt][nt][r];
            }
        }
    #pragma unroll
    for (int o = 32; o > 0; o >>= 1) loc += __shfl_xor(loc, o);
    if (lane == 0) red[w] = loc;
    __syncthreads();
    float tr = red[0] + red[1] + red[2] + red[3] + red[4] + red[5] + red[6] + red[7];

    // ---------- epilogue ----------
    float s     = sv[0];
    float inv   = s / tr;
    float onems = 1.f - s;
    float* outr = out + (size_t)b * 16384;
    float* outi = out + 8388608 + (size_t)b * 16384;

    #pragma unroll
    for (int mt = 0; mt < 4; ++mt)
        #pragma unroll
        for (int nt = 0; nt < 2; ++nt) {
            int colc = wn * 32 + nt * 16 + c16;
            #pragma unroll
            for (int r = 0; r < 4; ++r) {
                int row = wm * 64 + mt * 16 + g4 * 4 + r;
                float vr = sR[mt][nt][r] * inv;
                if (row == colc) vr += onems * pv[row];
                outr[row * 128 + colc] = vr;
                outi[row * 128 + colc] = sI[mt][nt][r] * inv;
            }
        }
}

extern "C" void kernel_launch(void* const* d_in, const int* in_sizes, int n_in,
                              void* d_out, int out_size, void* d_ws, size_t ws_size,
                              hipStream_t stream) {
    (void)in_sizes; (void)n_in; (void)out_size; (void)ws_size;
    const float* xr = (const float*)d_in[0];
    const float* xi = (const float*)d_in[1];
    const float* wt = (const float*)d_in[2];
    const float* rw = (const float*)d_in[3];
    const float* lm = (const float*)d_in[4];

    short* Ur  = (short*)d_ws;                        // 128x256 bf16 (64 KB)
    short* Ui  = Ur + 32768;                          // 64 KB
    float* pv  = (float*)((char*)d_ws + 131072);      // 128 f32
    float* sv  = pv + 128;                            // 1 f32
    short* Ypr = (short*)((char*)d_ws + 135168);      // 33.55 MB frag-packed Y
    short* Ypi = (short*)((char*)d_ws + 135168 + 33554432);
    float* o   = (float*)d_out;

    qprep_u<<<dim3(128), dim3(256), 0, stream>>>(wt, Ur, Ui);
    qprep_ps<<<dim3(1), dim3(64), 0, stream>>>(rw, lm, pv, sv);
    qk1<<<dim3(1024), dim3(512), 0, stream>>>(xr, xi, Ur, Ui, Ypr, Ypi);
    qk2<<<dim3(512), dim3(512), 0, stream>>>(Ur, Ui, Ypr, Ypi, pv, sv, o);
}

// Round 7
// 175.433 us; speedup vs baseline: 1.8593x; 1.8593x over previous
//
#include <hip/hip_runtime.h>
#include <hip/hip_bf16.h>

// QDense: out = s * (U X U^H)[:128,:128] / tr + (1-s) * diag(softmax(rand_w))
// B=512, D=256, O=128.
// Round-7: fused r3 dataflow + explicit X software pipeline.
//   1024 blocks (b = bx>>1, k'-half kh = bx&1), 512 thr, LDS 112 KB:
//     [0,65536):        U-half, 64 rows x 512 B, XOR-swizzled (r3-proven)
//     [65536,98304):    X slots[2], 16 KB each = R[64x128B] + I at +8192, swizzled
//     [98304,114688):   Yt (R at 98304, I at 106496), r3 layout
//   Pipeline: slice s = (jt=s>>3, ks=s&7): global->reg at phase s-4,
//   ds_write at phase s-1, MFMA-consume at phase s.  Counted vmcnt via
//   compiler (reg-staged); raw s_barrier + manual lgkmcnt(0) (NO __syncthreads
//   in the loop - it would drain vmcnt and kill the prefetch).
//   Trace via Q = (U^H U)^T folded into stage A (r3), Q prefetched 1 phase
//   ahead so its wait cannot drain X gens (vmcnt FIFO).

typedef __attribute__((ext_vector_type(4))) float f32x4;
typedef __attribute__((ext_vector_type(8))) short bf16x8;

static __device__ __forceinline__ short f2bf(float f) {   // prep kernels only
    unsigned u = __float_as_uint(f);
    u += 0x7fffu + ((u >> 16) & 1u);
    return (short)(u >> 16);
}

static __device__ __forceinline__ unsigned cvtpk2(float lo, float hi) {
    union { __hip_bfloat162 h; unsigned u; } c;
    c.h = __float22bfloat162_rn(float2{lo, hi});
    return c.u;
}

static __device__ __forceinline__ bf16x8 pack8(f32x4 a, f32x4 b) {
    union { unsigned u[4]; bf16x8 v; } r;
    r.u[0] = cvtpk2(a[0], a[1]);
    r.u[1] = cvtpk2(a[2], a[3]);
    r.u[2] = cvtpk2(b[0], b[1]);
    r.u[3] = cvtpk2(b[2], b[3]);
    return r.v;
}

static __device__ __forceinline__ f32x4 mfma16(bf16x8 a, bf16x8 b, f32x4 c) {
    return __builtin_amdgcn_mfma_f32_16x16x32_bf16(a, b, c, 0, 0, 0);
}

#define XGOFF(S) (((S) >> 3) * 16384 + ((S) & 7) * 32)   // floats (and shorts for Q)

// ---- prep kernels (r3 verbatim) ----
__global__ void qprep_u(const float* __restrict__ wt,
                        short* __restrict__ Ur, short* __restrict__ Ui) {
    int idx = blockIdx.x * 256 + threadIdx.x;
    float2 v = ((const float2*)wt)[idx];
    Ur[idx] = f2bf(v.x);
    Ui[idx] = f2bf(v.y);
}

__global__ void qprep_ps(const float* __restrict__ rw, const float* __restrict__ lm,
                         float* __restrict__ pv, float* __restrict__ sv) {
    int t = threadIdx.x;
    float w0 = rw[t], w1 = rw[t + 64];
    float m = fmaxf(w0, w1);
    #pragma unroll
    for (int o = 32; o > 0; o >>= 1) m = fmaxf(m, __shfl_xor(m, o));
    float e0 = expf(w0 - m), e1 = expf(w1 - m);
    float ss = e0 + e1;
    #pragma unroll
    for (int o = 32; o > 0; o >>= 1) ss += __shfl_xor(ss, o);
    pv[t] = e0 / ss;
    pv[t + 64] = e1 / ss;
    if (t == 0) sv[0] = 1.f / (1.f + expf(-lm[0]));
}

__global__ void qprep_q(const float* __restrict__ wt,
                        short* __restrict__ Qrb, short* __restrict__ Qib) {
    int j = blockIdx.x;
    int k = threadIdx.x;
    float ar = 0.f, ai = 0.f;
    for (int i = 0; i < 128; ++i) {
        float2 uk = ((const float2*)wt)[i * 256 + k];
        float2 uj = ((const float2*)wt)[i * 256 + j];
        ar += uk.x * uj.x + uk.y * uj.y;
        ai += uk.x * uj.y - uk.y * uj.x;
    }
    Qrb[j * 256 + k] = f2bf(ar);
    Qib[j * 256 + k] = f2bf(ai);
}

// ---- one pipeline phase (P = 0..31 compile-time) ----
template<int P>
static __device__ __forceinline__ void phaseT(
    char* smem, const float* xgR, const float* xgI, int stW,
    int rdo0, int rdo1, const short* qbr, const short* qbi,
    int kb, int c16, int g4, bool dotr,
    f32x4* genR, f32x4* genI, bf16x8* qgr, bf16x8* qgi,
    f32x4* yR, f32x4* yI, f32x4& tr4)
{
    // 1. ds_write slice P+1 (loaded 4 phases ago; compiler emits counted vmcnt)
    if (P + 1 < 32) {
        char* sb = smem + 65536 + ((P + 1) & 1) * 16384;
        *(f32x4*)(sb + stW)        = genR[(P + 1) & 3];
        *(f32x4*)(sb + 8192 + stW) = genI[(P + 1) & 3];
    }
    // 2. Q prefetch slice P+1 (before X gens: FIFO keeps its wait from draining them)
    if (dotr && (P + 1 < 32)) {
        qgr[(P + 1) & 1] = *(const bf16x8*)(qbr + XGOFF(P + 1));
        qgi[(P + 1) & 1] = *(const bf16x8*)(qbi + XGOFF(P + 1));
    }
    // 3. issue global loads for slice P+5 (anti-dep on step-1's gen: same slot mod 4)
    if (P + 5 < 32) {
        genR[(P + 5) & 3] = *(const f32x4*)(xgR + XGOFF(P + 5));
        genI[(P + 5) & 3] = *(const f32x4*)(xgI + XGOFF(P + 5));
    }
    asm volatile("" ::: "memory");   // pin loads: may not sink below this point
    // 4. consume slice P from slot[P&1]
    {
        char* rb = smem + 65536 + (P & 1) * 16384;
        f32x4 a0 = *(const f32x4*)(rb + rdo0);
        f32x4 a1 = *(const f32x4*)(rb + rdo1);
        f32x4 b0 = *(const f32x4*)(rb + 8192 + rdo0);
        f32x4 b1 = *(const f32x4*)(rb + 8192 + rdo1);
        bf16x8 axr  = pack8(a0, a1);
        bf16x8 axi  = pack8(b0, b1);
        bf16x8 axrn = axr ^ (short)0x8000;
        {
            const int kloc = kb + c16;
            const int uo = kloc * 512 + (((P & 7) * 64 + g4 * 16) ^ ((kloc & 7) << 4));
            bf16x8 bur = *(const bf16x8*)(smem + uo);
            bf16x8 bui = *(const bf16x8*)(smem + 32768 + uo);
            yR[0] = mfma16(axr,  bur, yR[0]);
            yR[0] = mfma16(axi,  bui, yR[0]);
            yI[0] = mfma16(axi,  bur, yI[0]);
            yI[0] = mfma16(axrn, bui, yI[0]);
        }
        {
            const int kloc = kb + 16 + c16;
            const int uo = kloc * 512 + (((P & 7) * 64 + g4 * 16) ^ ((kloc & 7) << 4));
            bf16x8 bur = *(const bf16x8*)(smem + uo);
            bf16x8 bui = *(const bf16x8*)(smem + 32768 + uo);
            yR[1] = mfma16(axr,  bur, yR[1]);
            yR[1] = mfma16(axi,  bui, yR[1]);
            yI[1] = mfma16(axi,  bur, yI[1]);
            yI[1] = mfma16(axrn, bui, yI[1]);
        }
        if (dotr) {
            bf16x8 axin = axi ^ (short)0x8000;
            tr4 = mfma16(axr,  qgr[P & 1], tr4);
            tr4 = mfma16(axin, qgi[P & 1], tr4);
        }
    }
    // 5. drain LDS ops, then raw barrier (vmcnt stays counted - prefetch lives on)
    asm volatile("s_waitcnt lgkmcnt(0)" ::: "memory");
    __builtin_amdgcn_sched_barrier(0);
    __builtin_amdgcn_s_barrier();
    __builtin_amdgcn_sched_barrier(0);
}

// ---- stage B compute for one jt (r3 verbatim, Yt at 98304/106496) ----
static __device__ __forceinline__ void stageB(
    char* smem, const short* Urg, const short* Uig, int jt,
    int wm, int wn, int c16, int g4,
    f32x4 (&sR)[2][2], f32x4 (&sI)[2][2])
{
    #pragma unroll
    for (int ks2 = 0; ks2 < 2; ++ks2) {
        bf16x8 aur[2], aui[2], auin[2];
        #pragma unroll
        for (int mt = 0; mt < 2; ++mt) {
            int i = wm * 32 + mt * 16 + c16;
            aur[mt]  = *(const bf16x8*)(Urg + (size_t)i * 256 + jt + ks2 * 32 + g4 * 8);
            aui[mt]  = *(const bf16x8*)(Uig + (size_t)i * 256 + jt + ks2 * 32 + g4 * 8);
            auin[mt] = aui[mt] ^ (short)0x8000;
        }
        #pragma unroll
        for (int nt2 = 0; nt2 < 2; ++nt2) {
            int kloc = wn * 32 + nt2 * 16 + c16;
            int off  = kloc * 128 + ((ks2 * 64 + g4 * 16) ^ ((kloc & 7) << 4));
            bf16x8 byr = *(const bf16x8*)(smem + 98304 + off);
            bf16x8 byi = *(const bf16x8*)(smem + 106496 + off);
            #pragma unroll
            for (int mt = 0; mt < 2; ++mt) {
                sR[mt][nt2] = mfma16(aur[mt],  byr, sR[mt][nt2]);
                sR[mt][nt2] = mfma16(auin[mt], byi, sR[mt][nt2]);
                sI[mt][nt2] = mfma16(aui[mt],  byr, sI[mt][nt2]);
                sI[mt][nt2] = mfma16(aur[mt],  byi, sI[mt][nt2]);
            }
        }
    }
}

// ---- Yt write + barrier + stage B, as a macro over literal JT ----
#define YT_AND_B(JT) do {                                                       \
    {                                                                           \
        const int klA = kb + c16;                                               \
        const int oA  = klA * 128 + ((ja * 2 + g4 * 8) ^ ((klA & 7) << 4));     \
        uint2 v;                                                                \
        v.x = cvtpk2(yR[0][0], yR[0][1]); v.y = cvtpk2(yR[0][2], yR[0][3]);     \
        *(uint2*)(smem + 98304 + oA) = v;                                       \
        v.x = cvtpk2(yI[0][0], yI[0][1]); v.y = cvtpk2(yI[0][2], yI[0][3]);     \
        *(uint2*)(smem + 106496 + oA) = v;                                      \
        const int klB = kb + 16 + c16;                                          \
        const int oB  = klB * 128 + ((ja * 2 + g4 * 8) ^ ((klB & 7) << 4));     \
        v.x = cvtpk2(yR[1][0], yR[1][1]); v.y = cvtpk2(yR[1][2], yR[1][3]);     \
        *(uint2*)(smem + 98304 + oB) = v;                                       \
        v.x = cvtpk2(yI[1][0], yI[1][1]); v.y = cvtpk2(yI[1][2], yI[1][3]);     \
        *(uint2*)(smem + 106496 + oB) = v;                                      \
    }                                                                           \
    asm volatile("s_waitcnt lgkmcnt(0)" ::: "memory");                          \
    __builtin_amdgcn_sched_barrier(0);                                          \
    __builtin_amdgcn_s_barrier();                                               \
    __builtin_amdgcn_sched_barrier(0);                                          \
    stageB(smem, Urg, Uig, (JT) * 64, wm, wn, c16, g4, sR, sI);                 \
    yR[0] = zero; yR[1] = zero; yI[0] = zero; yI[1] = zero;                     \
} while (0)

#define PH(P) phaseT<P>(smem, xgR, xgI, stW, rdo0, rdo1, qbr, qbi, kb, c16, g4, \
                        dotr, genR, genI, qgr, qgi, yR, yI, tr4)

// ---- main fused kernel ----
__global__ __launch_bounds__(512, 2) void qfused(
    const float* __restrict__ xr, const float* __restrict__ xi,
    const short* __restrict__ Urg, const short* __restrict__ Uig,
    const short* __restrict__ Qrb, const short* __restrict__ Qib,
    const float* __restrict__ pv, const float* __restrict__ sv,
    float* __restrict__ out)
{
    __shared__ __align__(16) char smem[114688];

    const int bx   = blockIdx.x;
    const int b    = bx >> 1;
    const int kh   = bx & 1;
    const int tid  = threadIdx.x;
    const int lane = tid & 63;
    const int w    = tid >> 6;
    const int c16  = lane & 15;
    const int g4   = lane >> 4;

    // ---- stage U-half into swizzled LDS (r3-proven) ----
    #pragma unroll
    for (int q = 0; q < 4; ++q) {
        int c    = tid + q * 512;
        int row  = c >> 5;
        int slot = c & 31;
        int ss   = slot ^ (row & 7);
        const short* sr = Urg + (size_t)(kh * 64 + row) * 256 + ss * 8;
        const short* si = Uig + (size_t)(kh * 64 + row) * 256 + ss * 8;
        *(bf16x8*)(smem + row * 512 + slot * 16)         = *(const bf16x8*)sr;
        *(bf16x8*)(smem + 32768 + row * 512 + slot * 16) = *(const bf16x8*)si;
    }

    const float* xrb = xr + ((size_t)b << 16);
    const float* xib = xi + ((size_t)b << 16);

    const int  ja   = (w & 3) * 16;
    const int  kb   = (w >> 2) * 32;
    const int  wm   = w >> 1;
    const int  wn   = w & 1;
    const bool dotr = (w < 4);

    // staging addresses (per-thread constants)
    const int rowW = w * 8 + (lane >> 3);
    const int cW   = lane & 7;
    const float* xgR = xrb + rowW * 256 + cW * 4;
    const float* xgI = xib + rowW * 256 + cW * 4;
    const int stW  = rowW * 128 + ((cW ^ (rowW & 7)) << 4);

    const int rA   = ja + c16;
    const int rdo0 = rA * 128 + (((2 * g4)     ^ (rA & 7)) << 4);
    const int rdo1 = rA * 128 + (((2 * g4 + 1) ^ (rA & 7)) << 4);

    const short* qbr = Qrb + (size_t)(ja + c16) * 256 + g4 * 8;
    const short* qbi = Qib + (size_t)(ja + c16) * 256 + g4 * 8;

    f32x4 zero = {0.f, 0.f, 0.f, 0.f};
    f32x4 sR[2][2], sI[2][2];
    #pragma unroll
    for (int m = 0; m < 2; ++m)
        #pragma unroll
        for (int n = 0; n < 2; ++n) { sR[m][n] = zero; sI[m][n] = zero; }
    f32x4 tr4 = zero;
    f32x4 yR[2], yI[2];
    yR[0] = zero; yR[1] = zero; yI[0] = zero; yI[1] = zero;

    f32x4 genR[4], genI[4];
    bf16x8 qgr[2], qgi[2];

    // ---- prime the pipeline: slices 0..4 in flight, slot0 written ----
    {
        f32x4 t0R = *(const f32x4*)(xgR + XGOFF(0));
        f32x4 t0I = *(const f32x4*)(xgI + XGOFF(0));
        genR[1] = *(const f32x4*)(xgR + XGOFF(1));
        genI[1] = *(const f32x4*)(xgI + XGOFF(1));
        genR[2] = *(const f32x4*)(xgR + XGOFF(2));
        genI[2] = *(const f32x4*)(xgI + XGOFF(2));
        genR[3] = *(const f32x4*)(xgR + XGOFF(3));
        genI[3] = *(const f32x4*)(xgI + XGOFF(3));
        genR[0] = *(const f32x4*)(xgR + XGOFF(4));
        genI[0] = *(const f32x4*)(xgI + XGOFF(4));
        if (dotr) {
            qgr[0] = *(const bf16x8*)(qbr + XGOFF(0));
            qgi[0] = *(const bf16x8*)(qbi + XGOFF(0));
        }
        *(f32x4*)(smem + 65536 + stW)        = t0R;
        *(f32x4*)(smem + 65536 + 8192 + stW) = t0I;
    }
    __syncthreads();   // one-time full drain; pipeline refills in phases 0-3

    PH(0);  PH(1);  PH(2);  PH(3);  PH(4);  PH(5);  PH(6);  PH(7);
    YT_AND_B(0);
    PH(8);  PH(9);  PH(10); PH(11); PH(12); PH(13); PH(14); PH(15);
    YT_AND_B(1);
    PH(16); PH(17); PH(18); PH(19); PH(20); PH(21); PH(22); PH(23);
    YT_AND_B(2);
    PH(24); PH(25); PH(26); PH(27); PH(28); PH(29); PH(30); PH(31);
    YT_AND_B(3);

    // ---- trace: extract diag of tr4, reduce over block ----
    float loc = (dotr && ((c16 >> 2) == g4)) ? tr4[c16 & 3] : 0.f;
    #pragma unroll
    for (int o = 32; o > 0; o >>= 1) loc += __shfl_xor(loc, o);
    __syncthreads();
    float* red = (float*)(smem + 65536);
    if (lane == 0) red[w] = loc;
    __syncthreads();
    float tr = red[0] + red[1] + red[2] + red[3] + red[4] + red[5] + red[6] + red[7];

    float s     = sv[0];
    float inv   = s / tr;
    float onems = 1.f - s;
    float* outr = out + (size_t)b * 16384;
    float* outi = out + 8388608 + (size_t)b * 16384;

    #pragma unroll
    for (int mt = 0; mt < 2; ++mt)
        #pragma unroll
        for (int nt2 = 0; nt2 < 2; ++nt2) {
            int colc = kh * 64 + wn * 32 + nt2 * 16 + c16;
            #pragma unroll
            for (int r = 0; r < 4; ++r) {
                int row = wm * 32 + mt * 16 + g4 * 4 + r;
                float vr = sR[mt][nt2][r] * inv;
                if (row == colc) vr += onems * pv[row];
                outr[row * 128 + colc] = vr;
                outi[row * 128 + colc] = sI[mt][nt2][r] * inv;
            }
        }
}

extern "C" void kernel_launch(void* const* d_in, const int* in_sizes, int n_in,
                              void* d_out, int out_size, void* d_ws, size_t ws_size,
                              hipStream_t stream) {
    (void)in_sizes; (void)n_in; (void)out_size; (void)ws_size;
    const float* xr = (const float*)d_in[0];
    const float* xi = (const float*)d_in[1];
    const float* wt = (const float*)d_in[2];
    const float* rw = (const float*)d_in[3];
    const float* lm = (const float*)d_in[4];

    short* Ur  = (short*)d_ws;                        // 128x256 bf16 (64 KB)
    short* Ui  = Ur + 32768;                          // 64 KB
    float* pv  = (float*)((char*)d_ws + 131072);      // 128 f32
    float* sv  = pv + 128;                            // 1 f32
    short* Qrb = (short*)((char*)d_ws + 135168);      // 256x256 bf16 (128 KB)
    short* Qib = (short*)((char*)d_ws + 266240);      // 128 KB
    float* o   = (float*)d_out;

    qprep_u<<<dim3(128), dim3(256), 0, stream>>>(wt, Ur, Ui);
    qprep_ps<<<dim3(1), dim3(64), 0, stream>>>(rw, lm, pv, sv);
    qprep_q<<<dim3(256), dim3(256), 0, stream>>>(wt, Qrb, Qib);
    qfused<<<dim3(1024), dim3(512), 0, stream>>>(xr, xi, Ur, Ui, Qrb, Qib, pv, sv, o);
}